// Round 10
// baseline (351.054 us; speedup 1.0000x reference)
//
#include <hip/hip_runtime.h>

typedef short  short8   __attribute__((ext_vector_type(8)));
typedef float  floatx4  __attribute__((ext_vector_type(4)));
typedef unsigned int uintx2 __attribute__((ext_vector_type(2)));

#define LOG2E_X2 2.8853900817779268f

// Inputs pre-scaled by 2*log2(e) (folded into W1/b1): tanh(a)=1-2/(exp2(y)+1).
__device__ __forceinline__ float tanh_pre(float y) {
    float e = __builtin_amdgcn_exp2f(y);
    return 1.0f - 2.0f * __builtin_amdgcn_rcpf(1.0f + e);
}

__device__ __forceinline__ unsigned short bf16rne(float f) {   // setup only
    unsigned u = __float_as_uint(f);
    u += 0x7FFFu + ((u >> 16) & 1u);
    return (unsigned short)(u >> 16);
}

// RNE-pack two f32 -> dword of 2 bf16 (lo=a, hi=b).
#if __has_builtin(__builtin_amdgcn_cvt_pk_bf16_f32)
__device__ __forceinline__ unsigned pk2(float a, float b) {
    auto r = __builtin_amdgcn_cvt_pk_bf16_f32(a, b);
    unsigned u; __builtin_memcpy(&u, &r, 4);
    return u;
}
#else
__device__ __forceinline__ unsigned pk2(float a, float b) {
    unsigned r;
    asm("v_cvt_pk_bf16_f32 %0, %1, %2" : "=v"(r) : "v"(a), "v"(b));
    return r;
}
#endif

// Unpack 4 bf16 (packed lo/hi per dword) -> floatx4, exact.
__device__ __forceinline__ floatx4 unpk4(uintx2 u) {
    floatx4 r;
    r[0] = __uint_as_float(u.x << 16);
    r[1] = __uint_as_float(u.x & 0xffff0000u);
    r[2] = __uint_as_float(u.y << 16);
    r[3] = __uint_as_float(u.y & 0xffff0000u);
    return r;
}

// Round 13: GRID RESTRUCTURE. Rows (N nodes) are independent; only weights are
// shared. Old: 512 blocks x 64 rows x 512 thr = 2 blocks/CU (grid-capped),
// 2 phase-locked barrier groups, tanh concentrated in 4/8 waves -> ~40% idle
// that 5 micro-optimizations (R7-R12) failed to recover.
// New: 2048 blocks x 16 rows x 256 thr, UNIFORM wave roles: each of 4 waves
// does {GEMM1 64-chan slice -> tanh(16 vals) -> Hs} bar {GEMM2 16-d slice ->
// RK4 -> Atile} bar. 4 blocks/CU (VGPR-capped) = 4 independent barrier
// groups; per-wave tanh burst 64 -> 16 values; per-CU totals unchanged.
// Per-row arithmetic identical to verified R12 path (Phi as kk=2 register
// fragment, b1 C-seed, GEMM2 kk=0..7, same tanh/pk2) -> absmax 0.03125.
// LDS/block ~11.8KB. VGPR target <=128 (launch_bounds(256,4));
// tripwire: VGPR>128 or scratch => occupancy collapse.
__global__ __launch_bounds__(256, 4) void ode_mfma(
    const float* __restrict__ s_in,  const float* __restrict__ t_in,
    const float* __restrict__ phi_in,const float* __restrict__ bfr_in,
    const float* __restrict__ w1_in, const float* __restrict__ b1_in,
    const float* __restrict__ w2_in, const float* __restrict__ b2_in,
    float* __restrict__ out)
{
    const int tid  = threadIdx.x;
    const int w    = tid >> 6;         // wave 0..3
    const int lane = tid & 63;
    const int l15  = lane & 15;
    const int q    = lane >> 4;
    const int wg   = blockIdx.x;       // 0..2047
    const int sb   = wg >> 7;          // (s,b) group 0..15
    const int n0   = (wg & 127) << 4;  // 16-row group within N=2048
    const int rowg0 = sb * 2048 + n0;

    __shared__ __align__(16) unsigned short Atile[16][72];   // x cols 0..63 (+pad)
    __shared__ __align__(16) unsigned short Hs[16][264];     // 256 h chans (+pad)
    __shared__ __align__(16) float b1s[256];
    __shared__ float dls[8];

    if (tid < 64) {
        floatx4 v = *(const floatx4*)(b1_in + tid * 4);
        v *= LOG2E_X2;
        *(floatx4*)&b1s[tid * 4] = v;
    }
    if (tid < 8) dls[tid] = t_in[sb * 9 + tid + 1] - t_in[sb * 9 + tid];

    // ---- persistent register fragments (per wave) ----
    // GEMM1: wave owns 64 h-channels [w*64, w*64+64): w1f[ht=4][kk=3].
    short8 w1f[4][3];
#pragma unroll
    for (int ht = 0; ht < 4; ++ht)
#pragma unroll
        for (int kk = 0; kk < 3; ++kk) {
            short8 f;
#pragma unroll
            for (int j = 0; j < 8; ++j) {
                int k = kk * 32 + q * 8 + j;
                int hc = w * 64 + ht * 16 + l15;
                f[j] = (short)bf16rne(w1_in[k * 256 + hc] * LOG2E_X2);
            }
            w1f[ht][kk] = f;
        }
    // GEMM2: wave owns 16 d-cols [w*16, w*16+16): w2f[kk=8].
    short8 w2f[8];
#pragma unroll
    for (int kk = 0; kk < 8; ++kk) {
        short8 f;
#pragma unroll
        for (int j = 0; j < 8; ++j) {
            int k = kk * 32 + q * 8 + j;
            f[j] = (short)bf16rne(w2_in[k * 64 + w * 16 + l15]);
        }
        w2f[kk] = f;
    }
    // Static Phi B-fragment (kk=2), identical across waves: 16 rows x 32 p.
    short8 xbP;
#pragma unroll
    for (int j = 0; j < 8; ++j)
        xbP[j] = (short)bf16rne(phi_in[(size_t)(rowg0 + l15) * 32 + q * 8 + j]);

    // RK4 state: lane owns (row = l15, d = w*16+q*4 .. +4).
    floatx4 xv, kacc;
    uintx2 fpk;
    {
        const int rg = rowg0 + l15;
        const int dh = w * 16 + q * 4;
        xv = *(const floatx4*)(s_in + (size_t)rg * 64 + dh);
        floatx4 fb = *(const floatx4*)(b2_in + dh)
                   + *(const floatx4*)(bfr_in + (size_t)rg * 64 + dh);
        fpk = (uintx2){ pk2(fb[0], fb[1]), pk2(fb[2], fb[3]) };
        uintx2 px = { pk2(xv[0], xv[1]), pk2(xv[2], xv[3]) };
        *(uintx2*)&Atile[l15][dh] = px;
    }

    __syncthreads();                   // init: Atile-x ready

#pragma unroll 1
    for (int blk = 0; blk < 8; ++blk) {
        const float dlt = dls[blk];
#pragma unroll 1
        for (int ii = 0; ii < 8; ++ii) {
            const int sub = ii & 3;

            // ---- GEMM1 (this wave's 64 h-chans, 16 rows) + tanh -> Hs ----
            {
                short8 xb0 = *(const short8*)&Atile[l15][q * 8];
                short8 xb1 = *(const short8*)&Atile[l15][32 + q * 8];
                floatx4 acc1[4];
#pragma unroll
                for (int ht = 0; ht < 4; ++ht) {
                    floatx4 bb = *(const floatx4*)&b1s[w * 64 + ht * 16 + q * 4];
                    acc1[ht] = __builtin_amdgcn_mfma_f32_16x16x32_bf16(
                        w1f[ht][0], xb0, bb, 0, 0, 0);
                }
#pragma unroll
                for (int ht = 0; ht < 4; ++ht)
                    acc1[ht] = __builtin_amdgcn_mfma_f32_16x16x32_bf16(
                        w1f[ht][1], xb1, acc1[ht], 0, 0, 0);
#pragma unroll
                for (int ht = 0; ht < 4; ++ht)
                    acc1[ht] = __builtin_amdgcn_mfma_f32_16x16x32_bf16(
                        w1f[ht][2], xbP, acc1[ht], 0, 0, 0);
#pragma unroll
                for (int ht = 0; ht < 4; ++ht) {
                    uintx2 hp = { pk2(tanh_pre(acc1[ht][0]), tanh_pre(acc1[ht][1])),
                                  pk2(tanh_pre(acc1[ht][2]), tanh_pre(acc1[ht][3])) };
                    *(uintx2*)&Hs[l15][w * 64 + ht * 16 + q * 4] = hp;
                }
            }
            __syncthreads();           // Hs complete (all 256 chans)

            // ---- GEMM2 (this wave's 16 d-cols, full K=256) + RK4 ----
            {
                const unsigned short* hrow = &Hs[l15][0];
                floatx4 acc2;
                {
                    short8 hb = *(const short8*)&hrow[q * 8];
                    acc2 = __builtin_amdgcn_mfma_f32_16x16x32_bf16(
                        w2f[0], hb, unpk4(fpk), 0, 0, 0);
                }
#pragma unroll
                for (int kk = 1; kk < 8; ++kk) {
                    short8 hb = *(const short8*)&hrow[kk * 32 + q * 8];
                    acc2 = __builtin_amdgcn_mfma_f32_16x16x32_bf16(
                        w2f[kk], hb, acc2, 0, 0, 0);
                }
                floatx4 kv = acc2 * dlt;
                floatx4 xe;
                if (sub == 0)      { kacc = kv;            xe = xv + 0.25f * kv; }
                else if (sub == 1) { kacc += 2.0f * kv;    xe = xv + 0.25f * kv; }
                else if (sub == 2) { kacc += 2.0f * kv;    xe = xv + 0.5f  * kv; }
                else               { xv += (kacc + kv) * (1.0f / 12.0f); xe = xv; }
                uintx2 px = { pk2(xe[0], xe[1]), pk2(xe[2], xe[3]) };
                *(uintx2*)&Atile[l15][w * 16 + q * 4] = px;
                if (ii == 7) {
                    const size_t ob = (size_t)((sb * 8 + blk) * 2048 + n0 + l15) * 64;
                    *(floatx4*)(out + ob + w * 16 + q * 4) = xv;
                }
            }
            __syncthreads();           // Atile-x(next) complete
        }
    }
}

extern "C" void kernel_launch(void* const* d_in, const int* in_sizes, int n_in,
                              void* d_out, int out_size, void* d_ws, size_t ws_size,
                              hipStream_t stream) {
    const float* s_in  = (const float*)d_in[0];
    const float* t_in  = (const float*)d_in[1];
    const float* phi   = (const float*)d_in[2];
    const float* bfr   = (const float*)d_in[3];
    const float* w1    = (const float*)d_in[4];
    const float* b1    = (const float*)d_in[5];
    const float* w2    = (const float*)d_in[6];
    const float* b2    = (const float*)d_in[7];
    ode_mfma<<<2048, 256, 0, stream>>>(s_in, t_in, phi, bfr, w1, b1, w2, b2, (float*)d_out);
}